// Round 5
// baseline (8139.274 us; speedup 1.0000x reference)
//
#include <hip/hip_runtime.h>

#define MTOT 131072   // b*n
#define NB   65536    // n per batch

// ---------------------------------------------------------------- pmin
__global__ void pmin_init_kernel(float* pmin){
    if (threadIdx.x < 6) pmin[threadIdx.x] = 2.0f;   // p in [0,1)
}

__global__ void pmin_kernel(const float* __restrict__ p, float* __restrict__ pmin){
    int bi = blockIdx.y;
    float m0 = 2.f, m1 = 2.f, m2 = 2.f;
    for (int ni = blockIdx.x * blockDim.x + threadIdx.x; ni < NB; ni += gridDim.x * blockDim.x){
        const float* pp = p + ((size_t)bi * NB + ni) * 3;
        m0 = fminf(m0, pp[0]); m1 = fminf(m1, pp[1]); m2 = fminf(m2, pp[2]);
    }
    #pragma unroll
    for (int o = 32; o > 0; o >>= 1){
        m0 = fminf(m0, __shfl_down(m0, o, 64));
        m1 = fminf(m1, __shfl_down(m1, o, 64));
        m2 = fminf(m2, __shfl_down(m2, o, 64));
    }
    if ((threadIdx.x & 63) == 0){
        atomicMin((int*)(pmin + bi*3 + 0), __float_as_int(m0));
        atomicMin((int*)(pmin + bi*3 + 1), __float_as_int(m1));
        atomicMin((int*)(pmin + bi*3 + 2), __float_as_int(m2));
    }
}

// ---------------------------------------------------------------- voxel scatter (atomicMax of ids)
// f64 voxelization (floor(p/g) in double) matches the numpy reference bit-exactly.
// USE_LDS=1 for coarse scales: per-block LDS grid absorbs same-address contention.
template<int USE_LDS>
__global__ void scatter_kernel(const float* __restrict__ p, const float* __restrict__ pmin,
                               int* __restrict__ vgrid, int* __restrict__ gcbuf,
                               double gd, int D){
    extern __shared__ int lgrid[];
    int m  = blockIdx.x * blockDim.x + threadIdx.x;
    int bi = m >> 16;
    double px = (double)p[m*3], py = (double)p[m*3+1], pz = (double)p[m*3+2];
    int gx = (int)floor(px / gd) - (int)floor((double)pmin[bi*3+0] / gd);
    int gy = (int)floor(py / gd) - (int)floor((double)pmin[bi*3+1] / gd);
    int gz = (int)floor(pz / gd) - (int)floor((double)pmin[bi*3+2] / gd);
    gcbuf[m] = (gx << 20) | (gy << 10) | gz;
    int cell = (gx * D + gy) * D + gz;

    if (!USE_LDS){
        atomicMax(vgrid + bi * D * D * D + cell, m);
        return;
    }
    int ncell = D * D * D;
    for (int c = threadIdx.x; c < ncell; c += 256) lgrid[c] = -1;
    __syncthreads();
    atomicMax(&lgrid[cell], m);
    __syncthreads();
    int* vg = vgrid + bi * ncell;
    for (int c = threadIdx.x; c < ncell; c += 256){
        int v = lgrid[c];
        if (v >= 0) atomicMax(vg + c, v);
    }
}

// ---------------------------------------------------------------- 27-tap neighbor table
__global__ void nbr_kernel(const int* __restrict__ gcbuf, const int* __restrict__ vgrid,
                           int* __restrict__ nbr, int D){
    int m  = blockIdx.x * blockDim.x + threadIdx.x;
    int bi = m >> 16;
    int pk = gcbuf[m];
    int gx = pk >> 20, gy = (pk >> 10) & 1023, gz = pk & 1023;
    #pragma unroll
    for (int k = 0; k < 27; k++){
        int v;
        if (k == 13){
            v = m;                                   // center tap: always self
        } else {
            int x = gx + (k/9) - 1;
            int y = gy + ((k/3)%3) - 1;
            int z = gz + (k%3) - 1;
            if (x < 0 || y < 0 || z < 0 || x >= D || y >= D || z >= D) v = -1;
            else v = vgrid[((bi * D + x) * D + y) * D + z];
        }
        nbr[k * MTOT + m] = v;
    }
}

// ---------------------------------------------------------------- fused mlp1 + per-scale mlp
__global__ void mlp_scale_kernel(const float* __restrict__ p, const float* __restrict__ w1,
                                 const float* __restrict__ b1,
                                 const float* __restrict__ w, const float* __restrict__ b,
                                 float* __restrict__ h0){
    int t = blockIdx.x * blockDim.x + threadIdx.x;
    int c = t & 31, m = t >> 5;
    float x = p[m*3+0], y = p[m*3+1], z = p[m*3+2];
    float acc = b[c];
    #pragma unroll
    for (int j = 0; j < 32; j++){
        float ptsj = b1[j] + x * w1[j] + y * w1[32 + j] + z * w1[64 + j];
        acc += ptsj * w[j*32 + c];
    }
    h0[t] = acc;
}

// ---------------------------------------------------------------- submanifold conv, 4-way channel split
// Thread layout: block = 64 points x 4 channel-groups; cg = tid>>6 (wave-uniform ->
// W pointer stays scalar-loadable), pm = tid&63 (gathers coalesce as before).
// Grid 2048 blocks = 8 blocks/CU -> ~32 waves/CU (was 2 blocks/CU, Occupancy 23.5%,
// VALUBusy 22.8%: latency-bound). Per-channel FMA order identical -> bitwise-same out.
// MODE 0: hout = conv(f) + f
// MODE 1: out += (conv(f) + f + h0) @ w2i      (RMW; LDS exchange for full 32-vec)
// MODE 2: out  = b2 + (conv(f) + f + h0) @ w2i (first scale: init, no out read)
template<int MODE>
__global__ __launch_bounds__(256)
void conv_kernel(const float* __restrict__ f, const float* __restrict__ W,
                 const float* __restrict__ bias, const int* __restrict__ nbr,
                 const float* __restrict__ h0, const float* __restrict__ w2i,
                 const float* __restrict__ b2,
                 float* __restrict__ hout, float* __restrict__ out)
{
    __shared__ float vsh[64][33];                  // +1 pad: kills 64-way bank conflict
    int pm = threadIdx.x & 63;
    int cg = threadIdx.x >> 6;                     // 0..3, wave-uniform
    int m  = blockIdx.x * 64 + pm;

    float acc[8];
    #pragma unroll
    for (int c = 0; c < 8; c++) acc[c] = bias[cg*8 + c];

    int nb = nbr[m];                               // tap 0 preloaded
    #pragma unroll 1
    for (int k = 0; k < 27; k++){
        int nb_next = (k < 26) ? nbr[(k+1)*MTOT + m] : -1;   // prefetch next tap id
        if (nb >= 0){
            const float4* fr = (const float4*)(f + (size_t)nb * 32);
            const float*  Wk = W + k*1024 + cg*8;  // W[k][j][cg*8+c]
            #pragma unroll
            for (int jq = 0; jq < 8; jq++){
                float4 fv = fr[jq];
                #pragma unroll
                for (int c = 0; c < 8; c++){
                    acc[c] += fv.x * Wk[(jq*4+0)*32 + c];
                    acc[c] += fv.y * Wk[(jq*4+1)*32 + c];
                    acc[c] += fv.z * Wk[(jq*4+2)*32 + c];
                    acc[c] += fv.w * Wk[(jq*4+3)*32 + c];
                }
            }
        }
        nb = nb_next;
    }

    const float* frow = f + (size_t)m * 32 + cg*8;
    if (MODE == 0){
        float* ho = hout + (size_t)m * 32 + cg*8;
        #pragma unroll
        for (int c = 0; c < 8; c++) ho[c] = acc[c] + frow[c];
    } else {
        const float* h0row = h0 + (size_t)m * 32 + cg*8;
        #pragma unroll
        for (int c = 0; c < 8; c++) vsh[pm][cg*8 + c] = acc[c] + frow[c] + h0row[c];
        __syncthreads();

        float o32[32];
        float* obase = out + (size_t)m * 128 + cg*32;
        if (MODE == 2){
            #pragma unroll
            for (int o = 0; o < 32; o++) o32[o] = b2[cg*32 + o];
        } else {
            #pragma unroll
            for (int q = 0; q < 8; q++){
                float4 t4 = ((const float4*)obase)[q];
                o32[q*4+0] = t4.x; o32[q*4+1] = t4.y; o32[q*4+2] = t4.z; o32[q*4+3] = t4.w;
            }
        }
        #pragma unroll
        for (int c = 0; c < 32; c++){
            float vc = vsh[pm][c];
            const float* w2r = w2i + c*128 + cg*32;
            #pragma unroll
            for (int o = 0; o < 32; o++) o32[o] += vc * w2r[o];
        }
        #pragma unroll
        for (int q = 0; q < 8; q++)
            ((float4*)obase)[q] = make_float4(o32[q*4+0], o32[q*4+1], o32[q*4+2], o32[q*4+3]);
    }
}

// ---------------------------------------------------------------- launch
extern "C" void kernel_launch(void* const* d_in, const int* in_sizes, int n_in,
                              void* d_out, int out_size, void* d_ws, size_t ws_size,
                              hipStream_t stream)
{
    // Bind inputs by unique element count (robust to ordering), positional fallback.
    static const int want[9] = {393216, 96, 32, 8192, 256, 442368, 512, 32768, 128};
    const void* bound[9];
    for (int i = 0; i < 9; i++) bound[i] = d_in[i];
    if (n_in == 9){
        for (int i = 0; i < 9; i++)
            for (int j = 0; j < 9; j++)
                if (in_sizes[j] == want[i]) { bound[i] = d_in[j]; break; }
    }
    const float* p      = (const float*)bound[0];
    const float* w1     = (const float*)bound[1];
    const float* b1     = (const float*)bound[2];
    const float* w_mlp  = (const float*)bound[3];
    const float* b_mlp  = (const float*)bound[4];
    const float* w_conv = (const float*)bound[5];
    const float* b_conv = (const float*)bound[6];
    const float* w2     = (const float*)bound[7];
    const float* b2     = (const float*)bound[8];
    float* out = (float*)d_out;

    // Workspace (46 MiB): h0 | h1 (vgrid aliases, lifetime-disjoint) | nbr | gcbuf | pmin
    char* ws = (char*)d_ws;
    float* h0    = (float*)(ws);
    float* h1    = (float*)(ws + 16777216);
    int*   vgrid = (int*)  (ws + 16777216);                 // alias of h1
    int*   nbr   = (int*)  (ws + 33554432);                 // 14,155,776 B
    int*   gcbuf = (int*)  (ws + 33554432 + 14155776);      // 524,288 B
    float* pmin  = (float*)(ws + 33554432 + 14155776 + 524288);

    static const double GS[8] = {0.01, 0.02, 0.04, 0.08, 0.16, 0.32, 0.64, 1.28};
    static const int    DS[8] = {101, 51, 26, 14, 8, 5, 3, 2};   // ceil(1/g)+1

    pmin_init_kernel<<<1, 64, 0, stream>>>(pmin);
    pmin_kernel<<<dim3(64, 2), 256, 0, stream>>>(p, pmin);

    for (int i = 0; i < 8; i++){
        int D = DS[i]; double gd = GS[i];
        int ncell = D * D * D;
        hipMemsetAsync(vgrid, 0xFF, (size_t)2*ncell*sizeof(int), stream);
        if (ncell <= 2744)
            scatter_kernel<1><<<MTOT/256, 256, ncell*sizeof(int), stream>>>(p, pmin, vgrid, gcbuf, gd, D);
        else
            scatter_kernel<0><<<MTOT/256, 256, 0, stream>>>(p, pmin, vgrid, gcbuf, gd, D);
        nbr_kernel<<<MTOT/256, 256, 0, stream>>>(gcbuf, vgrid, nbr, D);
        mlp_scale_kernel<<<(MTOT*32)/256, 256, 0, stream>>>(p, w1, b1, w_mlp + i*1024, b_mlp + i*32, h0);
        conv_kernel<0><<<MTOT/64, 256, 0, stream>>>(
            h0, w_conv + (size_t)(2*i)*27648, b_conv + (2*i)*32, nbr,
            nullptr, nullptr, nullptr, h1, nullptr);
        if (i == 0)
            conv_kernel<2><<<MTOT/64, 256, 0, stream>>>(
                h1, w_conv + (size_t)(2*i+1)*27648, b_conv + (2*i+1)*32, nbr,
                h0, w2 + i*32*128, b2, nullptr, out);
        else
            conv_kernel<1><<<MTOT/64, 256, 0, stream>>>(
                h1, w_conv + (size_t)(2*i+1)*27648, b_conv + (2*i+1)*32, nbr,
                h0, w2 + i*32*128, nullptr, nullptr, out);
    }
}

// Round 6
// 1999.552 us; speedup vs baseline: 4.0705x; 4.0705x over previous
//
#include <hip/hip_runtime.h>

#define MTOT 131072   // b*n
#define NB   65536    // n per batch

// ---------------------------------------------------------------- pmin
__global__ void pmin_init_kernel(float* pmin){
    if (threadIdx.x < 6) pmin[threadIdx.x] = 2.0f;   // p in [0,1)
}

__global__ void pmin_kernel(const float* __restrict__ p, float* __restrict__ pmin){
    int bi = blockIdx.y;
    float m0 = 2.f, m1 = 2.f, m2 = 2.f;
    for (int ni = blockIdx.x * blockDim.x + threadIdx.x; ni < NB; ni += gridDim.x * blockDim.x){
        const float* pp = p + ((size_t)bi * NB + ni) * 3;
        m0 = fminf(m0, pp[0]); m1 = fminf(m1, pp[1]); m2 = fminf(m2, pp[2]);
    }
    #pragma unroll
    for (int o = 32; o > 0; o >>= 1){
        m0 = fminf(m0, __shfl_down(m0, o, 64));
        m1 = fminf(m1, __shfl_down(m1, o, 64));
        m2 = fminf(m2, __shfl_down(m2, o, 64));
    }
    if ((threadIdx.x & 63) == 0){
        atomicMin((int*)(pmin + bi*3 + 0), __float_as_int(m0));
        atomicMin((int*)(pmin + bi*3 + 1), __float_as_int(m1));
        atomicMin((int*)(pmin + bi*3 + 2), __float_as_int(m2));
    }
}

// ---------------------------------------------------------------- voxel scatter (atomicMax of ids)
// f64 voxelization (floor(p/g) in double) matches the numpy f64 reference bit-exactly.
// USE_LDS=1 for coarse scales: per-block LDS grid absorbs same-address contention.
template<int USE_LDS>
__global__ void scatter_kernel(const float* __restrict__ p, const float* __restrict__ pmin,
                               int* __restrict__ vgrid, int* __restrict__ gcbuf,
                               double gd, int D){
    extern __shared__ int lgrid[];
    int m  = blockIdx.x * blockDim.x + threadIdx.x;
    int bi = m >> 16;
    double px = (double)p[m*3], py = (double)p[m*3+1], pz = (double)p[m*3+2];
    int gx = (int)floor(px / gd) - (int)floor((double)pmin[bi*3+0] / gd);
    int gy = (int)floor(py / gd) - (int)floor((double)pmin[bi*3+1] / gd);
    int gz = (int)floor(pz / gd) - (int)floor((double)pmin[bi*3+2] / gd);
    gcbuf[m] = (gx << 20) | (gy << 10) | gz;
    int cell = (gx * D + gy) * D + gz;

    if (!USE_LDS){
        atomicMax(vgrid + bi * D * D * D + cell, m);
        return;
    }
    int ncell = D * D * D;
    for (int c = threadIdx.x; c < ncell; c += 256) lgrid[c] = -1;
    __syncthreads();
    atomicMax(&lgrid[cell], m);
    __syncthreads();
    int* vg = vgrid + bi * ncell;
    for (int c = threadIdx.x; c < ncell; c += 256){
        int v = lgrid[c];
        if (v >= 0) atomicMax(vg + c, v);
    }
}

// ---------------------------------------------------------------- 27-tap neighbor table
__global__ void nbr_kernel(const int* __restrict__ gcbuf, const int* __restrict__ vgrid,
                           int* __restrict__ nbr, int D){
    int m  = blockIdx.x * blockDim.x + threadIdx.x;
    int bi = m >> 16;
    int pk = gcbuf[m];
    int gx = pk >> 20, gy = (pk >> 10) & 1023, gz = pk & 1023;
    #pragma unroll
    for (int k = 0; k < 27; k++){
        int v;
        if (k == 13){
            v = m;                                   // center tap: always self
        } else {
            int x = gx + (k/9) - 1;
            int y = gy + ((k/3)%3) - 1;
            int z = gz + (k%3) - 1;
            if (x < 0 || y < 0 || z < 0 || x >= D || y >= D || z >= D) v = -1;
            else v = vgrid[((bi * D + x) * D + y) * D + z];
        }
        nbr[k * MTOT + m] = v;
    }
}

// ---------------------------------------------------------------- fused mlp1 + per-scale mlp
__global__ void mlp_scale_kernel(const float* __restrict__ p, const float* __restrict__ w1,
                                 const float* __restrict__ b1,
                                 const float* __restrict__ w, const float* __restrict__ b,
                                 float* __restrict__ h0){
    int t = blockIdx.x * blockDim.x + threadIdx.x;
    int c = t & 31, m = t >> 5;
    float x = p[m*3+0], y = p[m*3+1], z = p[m*3+2];
    float acc = b[c];
    #pragma unroll
    for (int j = 0; j < 32; j++){
        float ptsj = b1[j] + x * w1[j] + y * w1[32 + j] + z * w1[64 + j];
        acc += ptsj * w[j*32 + c];
    }
    h0[t] = acc;
}

// ---------------------------------------------------------------- submanifold conv, 4-way TAP split
// Block = 64 points x 4 tap-groups (tg in 0..3 handles taps {7tg .. 7tg+6} (+6 for tg=3)).
// Each thread keeps the FULL acc[32] (same FMA intensity as round 4) and every
// (point,tap) f-row is gathered exactly once (no channel-split duplication).
// tg is forced to SGPR via readfirstlane -> W reads stay s_load (round-5 regression
// was W falling to per-lane VMEM: SGPR 112->32, VALUBusy 22.8->11.3).
// Cross-group reduce via padded LDS, tree ((bias+T0)+T2)+(T1+T3) (f32 reassoc ~1e-6).
// MODE 0: hout = conv(f) + f
// MODE 1: out += (conv(f) + f + h0) @ w2i
// MODE 2: out  = b2 + (conv(f) + f + h0) @ w2i   (first scale: init, no out read)
template<int MODE>
__global__ __launch_bounds__(256, 4)
void conv_kernel(const float* __restrict__ f, const float* __restrict__ W,
                 const float* __restrict__ bias, const int* __restrict__ nbr,
                 const float* __restrict__ h0, const float* __restrict__ w2i,
                 const float* __restrict__ b2,
                 float* __restrict__ hout, float* __restrict__ out)
{
    __shared__ float red[2][64][33];               // 16.9 KB; +1 pad -> <=2-way banks
    float (*vsh)[33] = red[0];                     // overlay, used after reduction

    int pm = threadIdx.x & 63;
    int tg = __builtin_amdgcn_readfirstlane(threadIdx.x >> 6);   // wave-uniform, exact
    int m  = blockIdx.x * 64 + pm;

    float acc[32];
    #pragma unroll
    for (int c = 0; c < 32; c++) acc[c] = (tg == 0) ? bias[c] : 0.0f;

    int k0 = tg * 7, kend = (tg < 3) ? k0 + 7 : 27;
    #pragma unroll 1
    for (int k = k0; k < kend; ++k){
        int nb = nbr[k * MTOT + m];
        if (nb >= 0){
            const float4* fr = (const float4*)(f + (size_t)nb * 32);
            const float*  Wk = W + k * 1024;       // scalar base (tg,k uniform)
            #pragma unroll
            for (int jq = 0; jq < 8; jq++){
                float4 fv = fr[jq];
                #pragma unroll
                for (int c = 0; c < 32; c++){
                    acc[c] += fv.x * Wk[(jq*4+0)*32 + c];
                    acc[c] += fv.y * Wk[(jq*4+1)*32 + c];
                    acc[c] += fv.z * Wk[(jq*4+2)*32 + c];
                    acc[c] += fv.w * Wk[(jq*4+3)*32 + c];
                }
            }
        }
    }

    // ---- tree reduce across the 4 tap-groups ----
    if (tg >= 2){
        #pragma unroll
        for (int c = 0; c < 32; c++) red[tg-2][pm][c] = acc[c];
    }
    __syncthreads();
    if (tg < 2){
        #pragma unroll
        for (int c = 0; c < 32; c++) acc[c] += red[tg][pm][c];
    }
    __syncthreads();
    if (tg == 1){
        #pragma unroll
        for (int c = 0; c < 32; c++) red[0][pm][c] = acc[c];
    }
    __syncthreads();

    if (tg == 0){
        const float* frow = f + (size_t)m * 32;
        #pragma unroll
        for (int c = 0; c < 32; c++) acc[c] += red[0][pm][c];
        if (MODE == 0){
            #pragma unroll
            for (int c = 0; c < 32; c++) vsh[pm][c] = acc[c] + frow[c];
        } else {
            const float* h0row = h0 + (size_t)m * 32;
            #pragma unroll
            for (int c = 0; c < 32; c++) vsh[pm][c] = acc[c] + frow[c] + h0row[c];
        }
    }
    __syncthreads();

    if (MODE == 0){
        // coalesced store of the block's contiguous 64x32 slab
        float* hb = hout + (size_t)blockIdx.x * 2048;
        int t = threadIdx.x;
        #pragma unroll
        for (int q = 0; q < 2; q++){
            int fi = q * 1024 + t * 4;             // float index in slab
            int pt = fi >> 5, ch = fi & 31;
            ((float4*)hb)[fi >> 2] =
                make_float4(vsh[pt][ch], vsh[pt][ch+1], vsh[pt][ch+2], vsh[pt][ch+3]);
        }
    } else {
        // each tap-group computes a disjoint 32-wide slice of the 128 outputs
        float o32[32];
        float* obase = out + (size_t)m * 128 + tg * 32;
        if (MODE == 2){
            #pragma unroll
            for (int o = 0; o < 32; o++) o32[o] = b2[tg*32 + o];
        } else {
            #pragma unroll
            for (int q = 0; q < 8; q++){
                float4 t4 = ((const float4*)obase)[q];
                o32[q*4+0] = t4.x; o32[q*4+1] = t4.y; o32[q*4+2] = t4.z; o32[q*4+3] = t4.w;
            }
        }
        #pragma unroll
        for (int c = 0; c < 32; c++){
            float vc = vsh[pm][c];
            const float* w2r = w2i + c*128 + tg*32;   // scalar base
            #pragma unroll
            for (int o = 0; o < 32; o++) o32[o] += vc * w2r[o];
        }
        #pragma unroll
        for (int q = 0; q < 8; q++)
            ((float4*)obase)[q] = make_float4(o32[q*4+0], o32[q*4+1], o32[q*4+2], o32[q*4+3]);
    }
}

// ---------------------------------------------------------------- launch
extern "C" void kernel_launch(void* const* d_in, const int* in_sizes, int n_in,
                              void* d_out, int out_size, void* d_ws, size_t ws_size,
                              hipStream_t stream)
{
    // Bind inputs by unique element count (robust to ordering), positional fallback.
    static const int want[9] = {393216, 96, 32, 8192, 256, 442368, 512, 32768, 128};
    const void* bound[9];
    for (int i = 0; i < 9; i++) bound[i] = d_in[i];
    if (n_in == 9){
        for (int i = 0; i < 9; i++)
            for (int j = 0; j < 9; j++)
                if (in_sizes[j] == want[i]) { bound[i] = d_in[j]; break; }
    }
    const float* p      = (const float*)bound[0];
    const float* w1     = (const float*)bound[1];
    const float* b1     = (const float*)bound[2];
    const float* w_mlp  = (const float*)bound[3];
    const float* b_mlp  = (const float*)bound[4];
    const float* w_conv = (const float*)bound[5];
    const float* b_conv = (const float*)bound[6];
    const float* w2     = (const float*)bound[7];
    const float* b2     = (const float*)bound[8];
    float* out = (float*)d_out;

    // Workspace (46 MiB): h0 | h1 (vgrid aliases, lifetime-disjoint) | nbr | gcbuf | pmin
    char* ws = (char*)d_ws;
    float* h0    = (float*)(ws);
    float* h1    = (float*)(ws + 16777216);
    int*   vgrid = (int*)  (ws + 16777216);                 // alias of h1
    int*   nbr   = (int*)  (ws + 33554432);                 // 14,155,776 B
    int*   gcbuf = (int*)  (ws + 33554432 + 14155776);      // 524,288 B
    float* pmin  = (float*)(ws + 33554432 + 14155776 + 524288);

    static const double GS[8] = {0.01, 0.02, 0.04, 0.08, 0.16, 0.32, 0.64, 1.28};
    static const int    DS[8] = {101, 51, 26, 14, 8, 5, 3, 2};   // ceil(1/g)+1

    pmin_init_kernel<<<1, 64, 0, stream>>>(pmin);
    pmin_kernel<<<dim3(64, 2), 256, 0, stream>>>(p, pmin);

    for (int i = 0; i < 8; i++){
        int D = DS[i]; double gd = GS[i];
        int ncell = D * D * D;
        hipMemsetAsync(vgrid, 0xFF, (size_t)2*ncell*sizeof(int), stream);
        if (ncell <= 2744)
            scatter_kernel<1><<<MTOT/256, 256, ncell*sizeof(int), stream>>>(p, pmin, vgrid, gcbuf, gd, D);
        else
            scatter_kernel<0><<<MTOT/256, 256, 0, stream>>>(p, pmin, vgrid, gcbuf, gd, D);
        nbr_kernel<<<MTOT/256, 256, 0, stream>>>(gcbuf, vgrid, nbr, D);
        mlp_scale_kernel<<<(MTOT*32)/256, 256, 0, stream>>>(p, w1, b1, w_mlp + i*1024, b_mlp + i*32, h0);
        conv_kernel<0><<<MTOT/64, 256, 0, stream>>>(
            h0, w_conv + (size_t)(2*i)*27648, b_conv + (2*i)*32, nbr,
            nullptr, nullptr, nullptr, h1, nullptr);
        if (i == 0)
            conv_kernel<2><<<MTOT/64, 256, 0, stream>>>(
                h1, w_conv + (size_t)(2*i+1)*27648, b_conv + (2*i+1)*32, nbr,
                h0, w2 + i*32*128, b2, nullptr, out);
        else
            conv_kernel<1><<<MTOT/64, 256, 0, stream>>>(
                h1, w_conv + (size_t)(2*i+1)*27648, b_conv + (2*i+1)*32, nbr,
                h0, w2 + i*32*128, nullptr, nullptr, out);
    }
}

// Round 7
// 1576.171 us; speedup vs baseline: 5.1640x; 1.2686x over previous
//
#include <hip/hip_runtime.h>

#define MTOT 131072   // b*n
#define NB   65536    // n per batch

typedef __attribute__((ext_vector_type(8))) __bf16 bf16x8;
typedef __attribute__((ext_vector_type(4))) float  f32x4;

// ---------------------------------------------------------------- pmin
__global__ void pmin_init_kernel(float* pmin){
    if (threadIdx.x < 6) pmin[threadIdx.x] = 2.0f;   // p in [0,1)
}

__global__ void pmin_kernel(const float* __restrict__ p, float* __restrict__ pmin){
    int bi = blockIdx.y;
    float m0 = 2.f, m1 = 2.f, m2 = 2.f;
    for (int ni = blockIdx.x * blockDim.x + threadIdx.x; ni < NB; ni += gridDim.x * blockDim.x){
        const float* pp = p + ((size_t)bi * NB + ni) * 3;
        m0 = fminf(m0, pp[0]); m1 = fminf(m1, pp[1]); m2 = fminf(m2, pp[2]);
    }
    #pragma unroll
    for (int o = 32; o > 0; o >>= 1){
        m0 = fminf(m0, __shfl_down(m0, o, 64));
        m1 = fminf(m1, __shfl_down(m1, o, 64));
        m2 = fminf(m2, __shfl_down(m2, o, 64));
    }
    if ((threadIdx.x & 63) == 0){
        atomicMin((int*)(pmin + bi*3 + 0), __float_as_int(m0));
        atomicMin((int*)(pmin + bi*3 + 1), __float_as_int(m1));
        atomicMin((int*)(pmin + bi*3 + 2), __float_as_int(m2));
    }
}

// ---------------------------------------------------------------- voxel scatter (atomicMax of ids)
// f64 voxelization (floor(p/g) in double) matches the numpy f64 reference bit-exactly.
template<int USE_LDS>
__global__ void scatter_kernel(const float* __restrict__ p, const float* __restrict__ pmin,
                               int* __restrict__ vgrid, int* __restrict__ gcbuf,
                               double gd, int D){
    extern __shared__ int lgrid[];
    int m  = blockIdx.x * blockDim.x + threadIdx.x;
    int bi = m >> 16;
    double px = (double)p[m*3], py = (double)p[m*3+1], pz = (double)p[m*3+2];
    int gx = (int)floor(px / gd) - (int)floor((double)pmin[bi*3+0] / gd);
    int gy = (int)floor(py / gd) - (int)floor((double)pmin[bi*3+1] / gd);
    int gz = (int)floor(pz / gd) - (int)floor((double)pmin[bi*3+2] / gd);
    gcbuf[m] = (gx << 20) | (gy << 10) | gz;
    int cell = (gx * D + gy) * D + gz;

    if (!USE_LDS){
        atomicMax(vgrid + bi * D * D * D + cell, m);
        return;
    }
    int ncell = D * D * D;
    for (int c = threadIdx.x; c < ncell; c += 256) lgrid[c] = -1;
    __syncthreads();
    atomicMax(&lgrid[cell], m);
    __syncthreads();
    int* vg = vgrid + bi * ncell;
    for (int c = threadIdx.x; c < ncell; c += 256){
        int v = lgrid[c];
        if (v >= 0) atomicMax(vg + c, v);
    }
}

// ---------------------------------------------------------------- 27-tap neighbor table
__global__ void nbr_kernel(const int* __restrict__ gcbuf, const int* __restrict__ vgrid,
                           int* __restrict__ nbr, int D){
    int m  = blockIdx.x * blockDim.x + threadIdx.x;
    int bi = m >> 16;
    int pk = gcbuf[m];
    int gx = pk >> 20, gy = (pk >> 10) & 1023, gz = pk & 1023;
    #pragma unroll
    for (int k = 0; k < 27; k++){
        int v;
        if (k == 13){
            v = m;
        } else {
            int x = gx + (k/9) - 1;
            int y = gy + ((k/3)%3) - 1;
            int z = gz + (k%3) - 1;
            if (x < 0 || y < 0 || z < 0 || x >= D || y >= D || z >= D) v = -1;
            else v = vgrid[((bi * D + x) * D + y) * D + z];
        }
        nbr[k * MTOT + m] = v;
    }
}

// ---------------------------------------------------------------- W -> transposed bf16 hi/lo planes
// w_conv[cv][k][j][c] (f32) -> wt[cv][k][c][j] hi/lo bf16 (B-fragment-friendly: per
// (k, col c) the 8 k-dim elems j are contiguous).
__global__ void wcv_kernel(const float* __restrict__ w_conv,
                           __bf16* __restrict__ wth, __bf16* __restrict__ wtl){
    int o = blockIdx.x * 256 + threadIdx.x;          // 442368 total
    int cv = o / 27648, r = o % 27648;
    int k = r / 1024, q = r % 1024, c = q / 32, j = q % 32;
    float x = w_conv[cv*27648 + k*1024 + j*32 + c];
    __bf16 hi = (__bf16)x;
    wth[o] = hi;
    wtl[o] = (__bf16)(x - (float)hi);
}

// ---------------------------------------------------------------- fused mlp1 + per-scale mlp -> bf16 hi/lo planes
__global__ void mlp_scale_kernel(const float* __restrict__ p, const float* __restrict__ w1,
                                 const float* __restrict__ b1,
                                 const float* __restrict__ w, const float* __restrict__ b,
                                 __bf16* __restrict__ h0h, __bf16* __restrict__ h0l){
    int t = blockIdx.x * blockDim.x + threadIdx.x;
    int c = t & 31, m = t >> 5;
    float x = p[m*3+0], y = p[m*3+1], z = p[m*3+2];
    float acc = b[c];
    #pragma unroll
    for (int j = 0; j < 32; j++){
        float ptsj = b1[j] + x * w1[j] + y * w1[32 + j] + z * w1[64 + j];
        acc += ptsj * w[j*32 + c];
    }
    __bf16 hi = (__bf16)acc;
    h0h[t] = hi;
    h0l[t] = (__bf16)(acc - (float)hi);
}

// ---------------------------------------------------------------- MFMA submanifold conv
// bf16 hi/lo (3-term) decomposition: conv error ~2^-17 relative (=f32-like).
// Wave = 32 points (2 row-blocks of 16) x 32 out channels (2 col-halves),
// 12 mfma_f32_16x16x32_bf16 per tap. Block = 4 waves = 128 points; grid 1024.
// Fragment maps (gfx950): A row=lane&15,k=(lane>>4)*8+e; B col=lane&15,k same;
// D col=lane&15,row=(lane>>4)*4+reg (m89-verified).
// MODE 0: h1 planes = conv(f) + f
// MODE 1: out += (conv(f) + f + h0) @ w2i
// MODE 2: out  = b2 + (conv(f) + f + h0) @ w2i  (first scale)
template<int MODE>
__global__ __launch_bounds__(256)
void conv_mfma_kernel(const __bf16* __restrict__ fh, const __bf16* __restrict__ fl,
                      const __bf16* __restrict__ wth, const __bf16* __restrict__ wtl,
                      const float* __restrict__ bias, const int* __restrict__ nbr,
                      const __bf16* __restrict__ r2h, const __bf16* __restrict__ r2l,
                      const float* __restrict__ w2i, const float* __restrict__ b2,
                      __bf16* __restrict__ outh, __bf16* __restrict__ outl,
                      float* __restrict__ out)
{
    __shared__ float vsh[128][33];
    int tid  = threadIdx.x;
    int lane = tid & 63, wid = tid >> 6;
    int col  = lane & 15, kq = lane >> 4;            // kq = 0..3 (k-chunk / row-group)
    int m0   = blockIdx.x * 128 + wid * 32;
    int ptA  = m0 + col, ptB = ptA + 16;

    float bv0 = bias[col], bv1 = bias[col + 16];
    f32x4 acc00 = {bv0,bv0,bv0,bv0}, acc01 = {bv1,bv1,bv1,bv1};
    f32x4 acc10 = {bv0,bv0,bv0,bv0}, acc11 = {bv1,bv1,bv1,bv1};

    const int fragoff = kq * 8;
    #pragma unroll 1
    for (int k = 0; k < 27; k++){
        int nb0 = nbr[k * MTOT + ptA];
        int nb1 = nbr[k * MTOT + ptB];
        size_t o0 = (size_t)(nb0 < 0 ? 0 : nb0) * 32 + fragoff;
        size_t o1 = (size_t)(nb1 < 0 ? 0 : nb1) * 32 + fragoff;
        bf16x8 a0h = *(const bf16x8*)(fh + o0);
        bf16x8 a0l = *(const bf16x8*)(fl + o0);
        bf16x8 a1h = *(const bf16x8*)(fh + o1);
        bf16x8 a1l = *(const bf16x8*)(fl + o1);
        bf16x8 z = {};
        if (nb0 < 0){ a0h = z; a0l = z; }
        if (nb1 < 0){ a1h = z; a1l = z; }

        const __bf16* wb = wth + (size_t)k*1024 + col*32 + fragoff;
        const __bf16* wc = wtl + (size_t)k*1024 + col*32 + fragoff;
        bf16x8 b0h = *(const bf16x8*)(wb);
        bf16x8 b1h = *(const bf16x8*)(wb + 512);     // col half 1 (+16 cols * 32)
        bf16x8 b0l = *(const bf16x8*)(wc);
        bf16x8 b1l = *(const bf16x8*)(wc + 512);

        acc00 = __builtin_amdgcn_mfma_f32_16x16x32_bf16(a0h, b0h, acc00, 0,0,0);
        acc00 = __builtin_amdgcn_mfma_f32_16x16x32_bf16(a0h, b0l, acc00, 0,0,0);
        acc00 = __builtin_amdgcn_mfma_f32_16x16x32_bf16(a0l, b0h, acc00, 0,0,0);
        acc01 = __builtin_amdgcn_mfma_f32_16x16x32_bf16(a0h, b1h, acc01, 0,0,0);
        acc01 = __builtin_amdgcn_mfma_f32_16x16x32_bf16(a0h, b1l, acc01, 0,0,0);
        acc01 = __builtin_amdgcn_mfma_f32_16x16x32_bf16(a0l, b1h, acc01, 0,0,0);
        acc10 = __builtin_amdgcn_mfma_f32_16x16x32_bf16(a1h, b0h, acc10, 0,0,0);
        acc10 = __builtin_amdgcn_mfma_f32_16x16x32_bf16(a1h, b0l, acc10, 0,0,0);
        acc10 = __builtin_amdgcn_mfma_f32_16x16x32_bf16(a1l, b0h, acc10, 0,0,0);
        acc11 = __builtin_amdgcn_mfma_f32_16x16x32_bf16(a1h, b1h, acc11, 0,0,0);
        acc11 = __builtin_amdgcn_mfma_f32_16x16x32_bf16(a1h, b1l, acc11, 0,0,0);
        acc11 = __builtin_amdgcn_mfma_f32_16x16x32_bf16(a1l, b1h, acc11, 0,0,0);
    }

    // stage D into LDS: row = wid*32 + rb*16 + kq*4 + r, col = ch*16 + (lane&15)
    #pragma unroll
    for (int r = 0; r < 4; r++){
        vsh[wid*32 + kq*4 + r][col]           = acc00[r];
        vsh[wid*32 + kq*4 + r][col + 16]      = acc01[r];
        vsh[wid*32 + 16 + kq*4 + r][col]      = acc10[r];
        vsh[wid*32 + 16 + kq*4 + r][col + 16] = acc11[r];
    }
    __syncthreads();

    if (MODE == 0){
        #pragma unroll
        for (int s = 0; s < 2; s++){
            int eidx = s*2048 + tid*8;
            int pt = eidx >> 5, c0 = eidx & 31;
            size_t g = (size_t)blockIdx.x * 4096 + eidx;
            bf16x8 rh = *(const bf16x8*)(fh + g);
            bf16x8 rl = *(const bf16x8*)(fl + g);
            bf16x8 oh8, ol8;
            #pragma unroll
            for (int j = 0; j < 8; j++){
                float v = vsh[pt][c0 + j] + (float)rh[j] + (float)rl[j];
                __bf16 hi = (__bf16)v;
                oh8[j] = hi;
                ol8[j] = (__bf16)(v - (float)hi);
            }
            *(bf16x8*)(outh + g) = oh8;
            *(bf16x8*)(outl + g) = ol8;
        }
    } else {
        // v = acc + f + h0 (both residuals from hi/lo planes), back into LDS
        #pragma unroll
        for (int s = 0; s < 2; s++){
            int eidx = s*2048 + tid*8;
            int pt = eidx >> 5, c0 = eidx & 31;
            size_t g = (size_t)blockIdx.x * 4096 + eidx;
            bf16x8 rh = *(const bf16x8*)(fh + g);
            bf16x8 rl = *(const bf16x8*)(fl + g);
            bf16x8 sh = *(const bf16x8*)(r2h + g);
            bf16x8 sl = *(const bf16x8*)(r2l + g);
            #pragma unroll
            for (int j = 0; j < 8; j++)
                vsh[pt][c0 + j] += (float)rh[j] + (float)rl[j] + (float)sh[j] + (float)sl[j];
        }
        __syncthreads();

        int pm = tid & 63;
        int tg = __builtin_amdgcn_readfirstlane(tid >> 6);   // wave-uniform
        #pragma unroll 1
        for (int half = 0; half < 2; half++){
            int ptl = half*64 + pm;
            size_t m = (size_t)blockIdx.x * 128 + ptl;
            float o32[32];
            float* obase = out + m*128 + tg*32;
            if (MODE == 2){
                #pragma unroll
                for (int o = 0; o < 32; o++) o32[o] = b2[tg*32 + o];
            } else {
                #pragma unroll
                for (int q = 0; q < 8; q++){
                    float4 t4 = ((const float4*)obase)[q];
                    o32[q*4+0] = t4.x; o32[q*4+1] = t4.y; o32[q*4+2] = t4.z; o32[q*4+3] = t4.w;
                }
            }
            #pragma unroll
            for (int c = 0; c < 32; c++){
                float vc = vsh[ptl][c];
                const float* w2r = w2i + c*128 + tg*32;      // scalar base
                #pragma unroll
                for (int o = 0; o < 32; o++) o32[o] += vc * w2r[o];
            }
            #pragma unroll
            for (int q = 0; q < 8; q++)
                ((float4*)obase)[q] = make_float4(o32[q*4+0], o32[q*4+1], o32[q*4+2], o32[q*4+3]);
        }
    }
}

// ---------------------------------------------------------------- launch
extern "C" void kernel_launch(void* const* d_in, const int* in_sizes, int n_in,
                              void* d_out, int out_size, void* d_ws, size_t ws_size,
                              hipStream_t stream)
{
    static const int want[9] = {393216, 96, 32, 8192, 256, 442368, 512, 32768, 128};
    const void* bound[9];
    for (int i = 0; i < 9; i++) bound[i] = d_in[i];
    if (n_in == 9){
        for (int i = 0; i < 9; i++)
            for (int j = 0; j < 9; j++)
                if (in_sizes[j] == want[i]) { bound[i] = d_in[j]; break; }
    }
    const float* p      = (const float*)bound[0];
    const float* w1     = (const float*)bound[1];
    const float* b1     = (const float*)bound[2];
    const float* w_mlp  = (const float*)bound[3];
    const float* b_mlp  = (const float*)bound[4];
    const float* w_conv = (const float*)bound[5];
    const float* b_conv = (const float*)bound[6];
    const float* w2     = (const float*)bound[7];
    const float* b2     = (const float*)bound[8];
    float* out = (float*)d_out;

    // Workspace (~49.5 MB): activation planes + nbr + W planes.
    // vgrid aliases h1h, gcbuf aliases h1l (lifetime-disjoint per scale:
    // both dead after nbr_kernel, before conv<0> writes h1 planes).
    char* ws = (char*)d_ws;
    __bf16* h0h  = (__bf16*)(ws);
    __bf16* h0l  = (__bf16*)(ws + 8388608);
    __bf16* h1h  = (__bf16*)(ws + 16777216);
    int*    vgrid= (int*)   (ws + 16777216);            // alias of h1h (8,242,408 B max)
    __bf16* h1l  = (__bf16*)(ws + 25165824);
    int*    gcbuf= (int*)   (ws + 25165824);            // alias of h1l (524,288 B)
    int*    nbr  = (int*)   (ws + 33554432);            // 14,155,776 B
    __bf16* wth  = (__bf16*)(ws + 47710208);            // 884,736 B
    __bf16* wtl  = (__bf16*)(ws + 48594944);            // 884,736 B
    float*  pmin = (float*) (ws + 49479680);

    static const double GS[8] = {0.01, 0.02, 0.04, 0.08, 0.16, 0.32, 0.64, 1.28};
    static const int    DS[8] = {101, 51, 26, 14, 8, 5, 3, 2};   // ceil(1/g)+1

    pmin_init_kernel<<<1, 64, 0, stream>>>(pmin);
    pmin_kernel<<<dim3(64, 2), 256, 0, stream>>>(p, pmin);
    wcv_kernel<<<1728, 256, 0, stream>>>(w_conv, wth, wtl);

    for (int i = 0; i < 8; i++){
        int D = DS[i]; double gd = GS[i];
        int ncell = D * D * D;
        hipMemsetAsync(vgrid, 0xFF, (size_t)2*ncell*sizeof(int), stream);
        if (ncell <= 2744)
            scatter_kernel<1><<<MTOT/256, 256, ncell*sizeof(int), stream>>>(p, pmin, vgrid, gcbuf, gd, D);
        else
            scatter_kernel<0><<<MTOT/256, 256, 0, stream>>>(p, pmin, vgrid, gcbuf, gd, D);
        nbr_kernel<<<MTOT/256, 256, 0, stream>>>(gcbuf, vgrid, nbr, D);
        mlp_scale_kernel<<<(MTOT*32)/256, 256, 0, stream>>>(p, w1, b1, w_mlp + i*1024, b_mlp + i*32, h0h, h0l);

        conv_mfma_kernel<0><<<MTOT/128, 256, 0, stream>>>(
            h0h, h0l, wth + (size_t)(2*i)*27648, wtl + (size_t)(2*i)*27648,
            b_conv + (2*i)*32, nbr, nullptr, nullptr, nullptr, nullptr,
            h1h, h1l, nullptr);

        if (i == 0)
            conv_mfma_kernel<2><<<MTOT/128, 256, 0, stream>>>(
                h1h, h1l, wth + (size_t)(2*i+1)*27648, wtl + (size_t)(2*i+1)*27648,
                b_conv + (2*i+1)*32, nbr, h0h, h0l, w2 + i*32*128, b2,
                nullptr, nullptr, out);
        else
            conv_mfma_kernel<1><<<MTOT/128, 256, 0, stream>>>(
                h1h, h1l, wth + (size_t)(2*i+1)*27648, wtl + (size_t)(2*i+1)*27648,
                b_conv + (2*i+1)*32, nbr, h0h, h0l, w2 + i*32*128, nullptr,
                nullptr, nullptr, out);
    }
}